// Round 1
// baseline (27.495 us; speedup 1.0000x reference)
//
#include <hip/hip_runtime.h>
#include <math.h>

#define BB 32
#define HH 256
#define NN 8192
#define CC 32            // chunks over N
#define CHUNK (NN / CC)  // 256 points per chunk

// ws layout (floats):
//   planes : BB*HH*4   at offset 0            (stored as float4 per plane)
//   loss   : BB*HH     at offset BB*HH*4
//   partial: BB*CC*HH  at offset BB*HH*5

__global__ __launch_bounds__(HH) void fit_planes_kernel(
    const float* __restrict__ pts, const float* __restrict__ target,
    const int* __restrict__ sidx, float* __restrict__ ws) {
  int b = blockIdx.x;
  int h = threadIdx.x;
  long base = ((long)b * HH + h) * 3;
  int i0 = sidx[base + 0], i1 = sidx[base + 1], i2 = sidx[base + 2];
  const float* pb = pts + (long)b * NN * 3;
  float p0x = pb[3 * i0], p0y = pb[3 * i0 + 1], p0z = pb[3 * i0 + 2];
  float p1x = pb[3 * i1], p1y = pb[3 * i1 + 1], p1z = pb[3 * i1 + 2];
  float p2x = pb[3 * i2], p2y = pb[3 * i2 + 1], p2z = pb[3 * i2 + 2];
  float v1x = p1x - p0x, v1y = p1y - p0y, v1z = p1z - p0z;
  float v2x = p2x - p0x, v2y = p2y - p0y, v2z = p2z - p0z;
  // cross product with explicit round-to-nearest ops (no FMA contraction):
  // degenerate triples must give EXACT zero to match numpy's all_zero path.
  float nx = __fsub_rn(__fmul_rn(v1y, v2z), __fmul_rn(v1z, v2y));
  float ny = __fsub_rn(__fmul_rn(v1z, v2x), __fmul_rn(v1x, v2z));
  float nz = __fsub_rn(__fmul_rn(v1x, v2y), __fmul_rn(v1y, v2x));
  float d = -(__fmul_rn(nx, p0x) + __fmul_rn(ny, p0y) + __fmul_rn(nz, p0z));
  if (nx == 0.0f && ny == 0.0f && nz == 0.0f && d == 0.0f) {
    nx = 1.0f; ny = 1.0f; nz = 1.0f; d = 1.0f;
  }
  float norm = sqrtf(nx * nx + ny * ny + nz * nz);
  nx /= norm; ny /= norm; nz /= norm; d /= norm;
  ((float4*)ws)[b * HH + h] = make_float4(nx, ny, nz, d);
  float tx = target[b * 3], ty = target[b * 3 + 1], tz = target[b * 3 + 2];
  float lm = (nx - tx) * (nx - tx) + (ny - ty) * (ny - ty) + (nz - tz) * (nz - tz);
  float lp = (nx + tx) * (nx + tx) + (ny + ty) * (ny + ty) + (nz + tz) * (nz + tz);
  ws[(size_t)BB * HH * 4 + b * HH + h] = fminf(lm, lp);
}

__global__ __launch_bounds__(HH) void score_partial_kernel(
    const float* __restrict__ pts, const float* __restrict__ ws,
    float* __restrict__ partial) {
  int chunk = blockIdx.x, b = blockIdx.y;
  int h = threadIdx.x;  // thread <-> plane
  __shared__ float4 sm4[CHUNK * 3 / 4];  // 256 points * 3 floats, 3KB
  float* sm = (float*)sm4;
  const float* src = pts + ((long)b * NN + (long)chunk * CHUNK) * 3;
  for (int j = h; j < CHUNK * 3; j += HH) sm[j] = src[j];
  float4 pl = ((const float4*)ws)[b * HH + h];
  __syncthreads();
  const float KC = -72.13475204444817f;  // -50 * log2(e)
  float a0 = 0.f, a1 = 0.f, a2 = 0.f, a3 = 0.f;
#pragma unroll 4
  for (int g = 0; g < CHUNK / 4; ++g) {
    float4 v0 = sm4[3 * g + 0];
    float4 v1 = sm4[3 * g + 1];
    float4 v2 = sm4[3 * g + 2];
    float t0 = fmaf(pl.x, v0.x, fmaf(pl.y, v0.y, fmaf(pl.z, v0.z, pl.w)));
    float t1 = fmaf(pl.x, v0.w, fmaf(pl.y, v1.x, fmaf(pl.z, v1.y, pl.w)));
    float t2 = fmaf(pl.x, v1.z, fmaf(pl.y, v1.w, fmaf(pl.z, v2.x, pl.w)));
    float t3 = fmaf(pl.x, v2.y, fmaf(pl.y, v2.z, fmaf(pl.z, v2.w, pl.w)));
    a0 += __builtin_amdgcn_exp2f(t0 * t0 * KC);
    a1 += __builtin_amdgcn_exp2f(t1 * t1 * KC);
    a2 += __builtin_amdgcn_exp2f(t2 * t2 * KC);
    a3 += __builtin_amdgcn_exp2f(t3 * t3 * KC);
  }
  partial[((long)b * CC + chunk) * HH + h] = (a0 + a1) + (a2 + a3);
}

__global__ __launch_bounds__(HH) void finalize_kernel(
    const float* __restrict__ ws, float* __restrict__ out) {
  int b = blockIdx.x, h = threadIdx.x;
  const float* lossArr = ws + (size_t)BB * HH * 4;
  const float* partial = ws + (size_t)BB * HH * 5;
  float s = 0.f;
#pragma unroll
  for (int c = 0; c < CC; ++c) s += partial[((long)b * CC + c) * HH + h];
  float l = lossArr[b * HH + h];

  __shared__ float sv[HH];
  __shared__ int si[HH];
  __shared__ float s1[HH];
  __shared__ float s2[HH];
  sv[h] = s; si[h] = h;
  __syncthreads();
  // argmax with first-index tie-break (matches jnp.argmax)
  for (int off = HH / 2; off > 0; off >>= 1) {
    if (h < off) {
      float o = sv[h + off]; int oi = si[h + off];
      if (o > sv[h] || (o == sv[h] && oi < si[h])) { sv[h] = o; si[h] = oi; }
    }
    __syncthreads();
  }
  float m = sv[0];
  int mi = si[0];
  __syncthreads();
  const float HALF_LOG2E = 0.5f * 1.4426950408889634f;
  float wv = __builtin_amdgcn_exp2f(HALF_LOG2E * (s - m));
  s1[h] = wv; s2[h] = wv * l;
  __syncthreads();
  for (int off = HH / 2; off > 0; off >>= 1) {
    if (h < off) { s1[h] += s1[h + off]; s2[h] += s2[h + off]; }
    __syncthreads();
  }
  if (h == 0) {
    out[b] = s2[0] / s1[0];                 // exp_loss
    out[BB + b] = lossArr[b * HH + mi];     // top_loss
    float4 p = ((const float4*)ws)[b * HH + mi];
    out[2 * BB + b * 3 + 0] = p.x;          // pred
    out[2 * BB + b * 3 + 1] = p.y;
    out[2 * BB + b * 3 + 2] = p.z;
  }
}

extern "C" void kernel_launch(void* const* d_in, const int* in_sizes, int n_in,
                              void* d_out, int out_size, void* d_ws, size_t ws_size,
                              hipStream_t stream) {
  const float* pts = (const float*)d_in[0];
  const float* target = (const float*)d_in[1];
  const int* sidx = (const int*)d_in[2];
  float* out = (float*)d_out;
  float* ws = (float*)d_ws;
  float* partial = ws + (size_t)BB * HH * 5;

  fit_planes_kernel<<<BB, HH, 0, stream>>>(pts, target, sidx, ws);
  score_partial_kernel<<<dim3(CC, BB), HH, 0, stream>>>(pts, ws, partial);
  finalize_kernel<<<BB, HH, 0, stream>>>(ws, out);
}